// Round 7
// baseline (422.089 us; speedup 1.0000x reference)
//
#include <hip/hip_runtime.h>
#include <hip/hip_bf16.h>

#define NN 8192
#define FIN 128
#define FOUT 64
#define JCH 256      // columns per chunk
#define NCH 32       // chunks (NCH*JCH == NN)
#define PSTR 264     // Pbuf row stride in shorts

typedef __attribute__((ext_vector_type(8))) short short8;
typedef __attribute__((ext_vector_type(4))) short short4v;
typedef __attribute__((ext_vector_type(4))) float floatx4;
typedef __attribute__((ext_vector_type(4))) int intx4;

__device__ __forceinline__ short f2bf_rne(float x) {
  union { float f; unsigned u; } c; c.f = x;
  unsigned r = c.u + 0x7fffu + ((c.u >> 16) & 1u);
  return (short)(r >> 16);
}
__device__ __forceinline__ float bf2f(short b) {
  union { unsigned u; float f; } c; c.u = ((unsigned)(unsigned short)b) << 16;
  return c.f;
}

// ---- adj (268 MB int32) -> bitmask (8.4 MB). Pure linear stream, fill-like.
// Layout: group g = 256 ints; word v (v=0..3) bit L = (adj[g*256 + L*4 + v] > 0).
__global__ __launch_bounds__(256) void convert_kernel(
    const int* __restrict__ adj, unsigned long long* __restrict__ mask) {
  const int gwave = (blockIdx.x * 256 + threadIdx.x) >> 6;  // 4096 waves
  const int lane = threadIdx.x & 63;
  const size_t g0 = (size_t)gwave * 64;  // 64 groups = 64 KB contiguous per wave
  for (int it = 0; it < 64; ++it) {
    const size_t grp = g0 + it;
    intx4 a = __builtin_nontemporal_load((const intx4*)(adj + grp * 256 + lane * 4));
    unsigned long long b0 = __ballot(a.x > 0);
    unsigned long long b1 = __ballot(a.y > 0);
    unsigned long long b2 = __ballot(a.z > 0);
    unsigned long long b3 = __ballot(a.w > 0);
    if (lane == 0) {
      mask[grp * 4 + 0] = b0;
      mask[grp * 4 + 1] = b1;
      mask[grp * 4 + 2] = b2;
      mask[grp * 4 + 3] = b3;
    }
  }
}

// Kernel A: h = x @ W^T (fp32), s_src/s_dst, and Hb = bf16 h pre-swizzled into
// MFMA-B-fragment order: Hb[((c*4 + ftile)*64 + quad*16 + fi)*8 + v] = h[c*32+quad*8+v][ftile*16+fi]
__global__ __launch_bounds__(256) void prep_kernel(
    const float* __restrict__ x, const float* __restrict__ W,
    const float* __restrict__ att_w,
    short* __restrict__ Hb, float* __restrict__ s_src, float* __restrict__ s_dst) {
  __shared__ float xs[16 * FIN];  // 8 KB: 16 rows of x
  const int t = threadIdx.x;
  const int bid = blockIdx.x;
#pragma unroll
  for (int i = 0; i < 8; ++i)
    xs[t + i * 256] = x[(size_t)bid * (16 * FIN) + t + i * 256];
  __syncthreads();
  const int w = t >> 6;     // wave handles rows w*4 .. w*4+3
  const int f = t & 63;     // lane == output feature
  const float4* Wf4 = (const float4*)(W + f * FIN);
  const float4* xr0 = (const float4*)(xs + (w * 4 + 0) * FIN);
  const float4* xr1 = (const float4*)(xs + (w * 4 + 1) * FIN);
  const float4* xr2 = (const float4*)(xs + (w * 4 + 2) * FIN);
  const float4* xr3 = (const float4*)(xs + (w * 4 + 3) * FIN);
  float h0 = 0.f, h1 = 0.f, h2 = 0.f, h3 = 0.f;
#pragma unroll
  for (int k = 0; k < FIN / 4; ++k) {
    float4 wv = Wf4[k];
    float4 v0 = xr0[k], v1 = xr1[k], v2 = xr2[k], v3 = xr3[k];
    h0 = fmaf(v0.x, wv.x, h0); h0 = fmaf(v0.y, wv.y, h0);
    h0 = fmaf(v0.z, wv.z, h0); h0 = fmaf(v0.w, wv.w, h0);
    h1 = fmaf(v1.x, wv.x, h1); h1 = fmaf(v1.y, wv.y, h1);
    h1 = fmaf(v1.z, wv.z, h1); h1 = fmaf(v1.w, wv.w, h1);
    h2 = fmaf(v2.x, wv.x, h2); h2 = fmaf(v2.y, wv.y, h2);
    h2 = fmaf(v2.z, wv.z, h2); h2 = fmaf(v2.w, wv.w, h2);
    h3 = fmaf(v3.x, wv.x, h3); h3 = fmaf(v3.y, wv.y, h3);
    h3 = fmaf(v3.z, wv.z, h3); h3 = fmaf(v3.w, wv.w, h3);
  }
  const float asrc = att_w[f];
  const float adst = att_w[FOUT + f];
  float hv[4] = {h0, h1, h2, h3};
#pragma unroll
  for (int g = 0; g < 4; ++g) {
    float v1 = hv[g] * asrc;
    float v2 = hv[g] * adst;
#pragma unroll
    for (int off = 32; off > 0; off >>= 1) {
      v1 += __shfl_xor(v1, off, 64);
      v2 += __shfl_xor(v2, off, 64);
    }
    const int r = bid * 16 + w * 4 + g;
    if (f == 0) { s_src[r] = v1; s_dst[r] = v2; }
    const int c = r >> 5;
    const int quad = (r >> 3) & 3;
    const int vv = r & 7;
    const int tile = f >> 4;
    const int fi = f & 15;
    Hb[(((c * 4 + tile) * 64) + quad * 16 + fi) * 8 + vv] = f2bf_rne(hv[g]);
  }
}

// p for 4 consecutive columns of one row; mask bits pre-extracted (bit v of `bits`)
__device__ __forceinline__ short4v pcalc_m(float ssrc, unsigned bits, float4 s, float& dsum) {
  float svv[4] = {s.x, s.y, s.z, s.w};
  short4v r;
#pragma unroll
  for (int v = 0; v < 4; ++v) {
    float tt = ssrc + svv[v];
    float e = fmaxf(tt, 0.f) + 0.01f * fminf(tt, 0.f);  // leaky_relu
    float p = __expf(e);
    p = ((bits >> v) & 1u) ? p : 0.f;
    short bb = f2bf_rne(p);
    r[v] = bb;
    dsum += bf2f(bb);  // denominator from bf16-rounded weight: exact normalization
  }
  return r;
}

// gat v4: identical MFMA/LDS structure to R5 (best), but the K-loop consumes the
// 8.4 MB bitmask instead of the 268 MB adj stream -> no HBM stream in the loop.
// Block = 16 rows, 8 waves; wave w produces p for rows 2w,2w+1 and consumes the
// k-strip j in [w*32, w*32+32) of each 256-j chunk x 4 feature tiles.
__global__ __launch_bounds__(512, 4) void gat_kernel(
    const unsigned long long* __restrict__ mask, const short8* __restrict__ Hb,
    const float* __restrict__ s_src, const float* __restrict__ s_dst,
    float* __restrict__ out) {
  __shared__ short Pbuf[2][16][PSTR];  // 16.5 KB: p-values, double-buffered
  __shared__ float part[8][16][64];    // 32 KB: per-wave partial numerators
  __shared__ float dden[16];           // full row denominators
  const int tid = threadIdx.x;
  const int w = tid >> 6;
  const int lane = tid & 63;
  const int m = lane & 15;
  const int quad = lane >> 4;
  const int bid = blockIdx.x;
  const int i0 = bid * 16;
  const int rA = 2 * w, rB = 2 * w + 1;
  const float ssA = s_src[i0 + rA];
  const float ssB = s_src[i0 + rB];
  const unsigned long long* mrowA = mask + (size_t)(i0 + rA) * (NN / 64);
  const unsigned long long* mrowB = mask + (size_t)(i0 + rB) * (NN / 64);
  const float* sdp = s_dst + lane * 4;

  floatx4 acc0 = {0.f, 0.f, 0.f, 0.f};
  floatx4 acc1 = acc0, acc2 = acc0, acc3 = acc0;
  float dsA = 0.f, dsB = 0.f;

  // ---- prologue: produce chunk cc(0) into buf0 ----
  {
    const int c0 = bid & (NCH - 1);
    unsigned long long wA0 = mrowA[c0 * 4], wA1 = mrowA[c0 * 4 + 1],
                       wA2 = mrowA[c0 * 4 + 2], wA3 = mrowA[c0 * 4 + 3];
    unsigned long long wB0 = mrowB[c0 * 4], wB1 = mrowB[c0 * 4 + 1],
                       wB2 = mrowB[c0 * 4 + 2], wB3 = mrowB[c0 * 4 + 3];
    float4 s0 = *(const float4*)(sdp + c0 * JCH);
    unsigned bA = (unsigned)((wA0 >> lane) & 1) | ((unsigned)((wA1 >> lane) & 1) << 1)
                | ((unsigned)((wA2 >> lane) & 1) << 2) | ((unsigned)((wA3 >> lane) & 1) << 3);
    unsigned bB = (unsigned)((wB0 >> lane) & 1) | ((unsigned)((wB1 >> lane) & 1) << 1)
                | ((unsigned)((wB2 >> lane) & 1) << 2) | ((unsigned)((wB3 >> lane) & 1) << 3);
    *(short4v*)&Pbuf[0][rA][lane * 4] = pcalc_m(ssA, bA, s0, dsA);
    *(short4v*)&Pbuf[0][rB][lane * 4] = pcalc_m(ssB, bB, s0, dsB);
  }

  for (int c = 0; c < NCH; ++c) {
    __syncthreads();  // Pbuf[c&1] produced; Pbuf[(c+1)&1] free
    const int cc = (c + bid) & (NCH - 1);
    // Hb B-fragments for this chunk's k-strip (L2-resident; issue first)
    const short8* hp = Hb + (size_t)(cc * 8 + w) * 256 + lane;
    short8 h0 = hp[0], h1 = hp[64], h2 = hp[128], h3 = hp[192];
    // produce chunk c+1 (mask + s_dst are cache-resident; no deep pipeline needed)
    if (c + 1 < NCH) {
      const int c1 = (c + 1 + bid) & (NCH - 1);
      unsigned long long wA0 = mrowA[c1 * 4], wA1 = mrowA[c1 * 4 + 1],
                         wA2 = mrowA[c1 * 4 + 2], wA3 = mrowA[c1 * 4 + 3];
      unsigned long long wB0 = mrowB[c1 * 4], wB1 = mrowB[c1 * 4 + 1],
                         wB2 = mrowB[c1 * 4 + 2], wB3 = mrowB[c1 * 4 + 3];
      float4 s0 = *(const float4*)(sdp + c1 * JCH);
      unsigned bA = (unsigned)((wA0 >> lane) & 1) | ((unsigned)((wA1 >> lane) & 1) << 1)
                  | ((unsigned)((wA2 >> lane) & 1) << 2) | ((unsigned)((wA3 >> lane) & 1) << 3);
      unsigned bB = (unsigned)((wB0 >> lane) & 1) | ((unsigned)((wB1 >> lane) & 1) << 1)
                  | ((unsigned)((wB2 >> lane) & 1) << 2) | ((unsigned)((wB3 >> lane) & 1) << 3);
      *(short4v*)&Pbuf[(c + 1) & 1][rA][lane * 4] = pcalc_m(ssA, bA, s0, dsA);
      *(short4v*)&Pbuf[(c + 1) & 1][rB][lane * 4] = pcalc_m(ssB, bB, s0, dsB);
    }
    // A-fragment from LDS (chunk c), then MFMA (waits Hb only)
    short8 af = *(const short8*)&Pbuf[c & 1][m][w * 32 + quad * 8];
    acc0 = __builtin_amdgcn_mfma_f32_16x16x32_bf16(af, h0, acc0, 0, 0, 0);
    acc1 = __builtin_amdgcn_mfma_f32_16x16x32_bf16(af, h1, acc1, 0, 0, 0);
    acc2 = __builtin_amdgcn_mfma_f32_16x16x32_bf16(af, h2, acc2, 0, 0, 0);
    acc3 = __builtin_amdgcn_mfma_f32_16x16x32_bf16(af, h3, acc3, 0, 0, 0);
  }

  // full row denominators: wave w produced ALL of rows 2w,2w+1
#pragma unroll
  for (int off = 1; off < 64; off <<= 1) {
    dsA += __shfl_xor(dsA, off, 64);
    dsB += __shfl_xor(dsB, off, 64);
  }
  if (lane == 0) { dden[rA] = dsA; dden[rB] = dsB; }

  // C/D layout: col = lane&15 (feature within tile), row = quad*4 + reg
  const int col = lane & 15;
#pragma unroll
  for (int rg = 0; rg < 4; ++rg) {
    part[w][quad * 4 + rg][col]      = acc0[rg];
    part[w][quad * 4 + rg][16 + col] = acc1[rg];
    part[w][quad * 4 + rg][32 + col] = acc2[rg];
    part[w][quad * 4 + rg][48 + col] = acc3[rg];
  }
  __syncthreads();

  // epilogue: sum 8 wave-partials (disjoint j), normalize, ELU, coalesced store
  for (int idx = tid; idx < 16 * 64; idx += 512) {
    int mr = idx >> 6, fc = idx & 63;
    float num = 0.f;
#pragma unroll
    for (int ww = 0; ww < 8; ++ww) num += part[ww][mr][fc];
    float o = num / dden[mr];
    o = (o > 0.f) ? o : (__expf(o) - 1.f);
    out[(size_t)(i0 + mr) * FOUT + fc] = o;
  }
}

extern "C" void kernel_launch(void* const* d_in, const int* in_sizes, int n_in,
                              void* d_out, int out_size, void* d_ws, size_t ws_size,
                              hipStream_t stream) {
  const float* x     = (const float*)d_in[0];
  const int*   adj   = (const int*)d_in[1];
  const float* W     = (const float*)d_in[2];
  const float* att_w = (const float*)d_in[3];
  float* out = (float*)d_out;
  char* ws = (char*)d_ws;
  short* Hb = (short*)ws;                                   // 1 MB bf16 swizzled h
  float* s_src = (float*)(ws + (size_t)NN * FOUT * sizeof(short));
  float* s_dst = s_src + NN;
  unsigned long long* mask = (unsigned long long*)(ws + (2u << 20));  // 8.4 MB bitmask
  convert_kernel<<<1024, 256, 0, stream>>>(adj, mask);
  prep_kernel<<<NN / 16, 256, 0, stream>>>(x, W, att_w, Hb, s_src, s_dst);
  gat_kernel<<<NN / 16, 512, 0, stream>>>(mask, (const short8*)Hb, s_src, s_dst, out);
}

// Round 8
// 401.330 us; speedup vs baseline: 1.0517x; 1.0517x over previous
//
#include <hip/hip_runtime.h>
#include <hip/hip_bf16.h>

#define NN 8192
#define FIN 128
#define FOUT 64
#define PADW 260   // maskS row stride in u32 (256+4: 16B-aligned rows, 2-way banks max)

typedef __attribute__((ext_vector_type(8))) short short8;
typedef __attribute__((ext_vector_type(4))) float floatx4;

__device__ __forceinline__ short f2bf_rne(float x) {
  union { float f; unsigned u; } c; c.f = x;
  unsigned r = c.u + 0x7fffu + ((c.u >> 16) & 1u);
  return (short)(r >> 16);
}

// ---- adj (268 MB int32) -> straight bitmask (8 MB): bit j of row r's word wi
// (u32) = adj[r][wi*32 + j']. Wave q handles row q: 32 iters x (4 dword loads
// -> 4 ballots -> 4 u64 words). Prefetch 1 iter ahead (8 loads in flight).
__global__ __launch_bounds__(256) void convert_kernel(
    const int* __restrict__ adj, unsigned long long* __restrict__ mask) {
  const int q = (blockIdx.x * 256 + threadIdx.x) >> 6;  // 8192 waves == rows
  const int lane = threadIdx.x & 63;
  const int* rp = adj + (size_t)q * NN + lane;
  int c0 = __builtin_nontemporal_load(rp + 0);
  int c1 = __builtin_nontemporal_load(rp + 64);
  int c2 = __builtin_nontemporal_load(rp + 128);
  int c3 = __builtin_nontemporal_load(rp + 192);
  unsigned long long* mp = mask + (size_t)q * (NN / 64);
  for (int i = 0; i < 32; ++i) {
    int n0, n1, n2, n3;
    if (i + 1 < 32) {
      const int* np = rp + (i + 1) * 256;
      n0 = __builtin_nontemporal_load(np + 0);
      n1 = __builtin_nontemporal_load(np + 64);
      n2 = __builtin_nontemporal_load(np + 128);
      n3 = __builtin_nontemporal_load(np + 192);
    }
    unsigned long long b0 = __ballot(c0 > 0);
    unsigned long long b1 = __ballot(c1 > 0);
    unsigned long long b2 = __ballot(c2 > 0);
    unsigned long long b3 = __ballot(c3 > 0);
    if (lane == 0) {
      mp[i * 4 + 0] = b0; mp[i * 4 + 1] = b1;
      mp[i * 4 + 2] = b2; mp[i * 4 + 3] = b3;
    }
    c0 = n0; c1 = n1; c2 = n2; c3 = n3;
  }
}

// Kernel A: h = x @ W^T (fp32), s_src/s_dst, and Hb = bf16 h pre-swizzled into
// MFMA-B-fragment order: Hb[((c*4 + ftile)*64 + quad*16 + fi)*8 + v] = h[c*32+quad*8+v][ftile*16+fi]
__global__ __launch_bounds__(256) void prep_kernel(
    const float* __restrict__ x, const float* __restrict__ W,
    const float* __restrict__ att_w,
    short* __restrict__ Hb, float* __restrict__ s_src, float* __restrict__ s_dst) {
  __shared__ float xs[16 * FIN];  // 8 KB: 16 rows of x
  const int t = threadIdx.x;
  const int bid = blockIdx.x;
#pragma unroll
  for (int i = 0; i < 8; ++i)
    xs[t + i * 256] = x[(size_t)bid * (16 * FIN) + t + i * 256];
  __syncthreads();
  const int w = t >> 6;     // wave handles rows w*4 .. w*4+3
  const int f = t & 63;     // lane == output feature
  const float4* Wf4 = (const float4*)(W + f * FIN);
  const float4* xr0 = (const float4*)(xs + (w * 4 + 0) * FIN);
  const float4* xr1 = (const float4*)(xs + (w * 4 + 1) * FIN);
  const float4* xr2 = (const float4*)(xs + (w * 4 + 2) * FIN);
  const float4* xr3 = (const float4*)(xs + (w * 4 + 3) * FIN);
  float h0 = 0.f, h1 = 0.f, h2 = 0.f, h3 = 0.f;
#pragma unroll
  for (int k = 0; k < FIN / 4; ++k) {
    float4 wv = Wf4[k];
    float4 v0 = xr0[k], v1 = xr1[k], v2 = xr2[k], v3 = xr3[k];
    h0 = fmaf(v0.x, wv.x, h0); h0 = fmaf(v0.y, wv.y, h0);
    h0 = fmaf(v0.z, wv.z, h0); h0 = fmaf(v0.w, wv.w, h0);
    h1 = fmaf(v1.x, wv.x, h1); h1 = fmaf(v1.y, wv.y, h1);
    h1 = fmaf(v1.z, wv.z, h1); h1 = fmaf(v1.w, wv.w, h1);
    h2 = fmaf(v2.x, wv.x, h2); h2 = fmaf(v2.y, wv.y, h2);
    h2 = fmaf(v2.z, wv.z, h2); h2 = fmaf(v2.w, wv.w, h2);
    h3 = fmaf(v3.x, wv.x, h3); h3 = fmaf(v3.y, wv.y, h3);
    h3 = fmaf(v3.z, wv.z, h3); h3 = fmaf(v3.w, wv.w, h3);
  }
  const float asrc = att_w[f];
  const float adst = att_w[FOUT + f];
  float hv[4] = {h0, h1, h2, h3};
#pragma unroll
  for (int g = 0; g < 4; ++g) {
    float v1 = hv[g] * asrc;
    float v2 = hv[g] * adst;
#pragma unroll
    for (int off = 32; off > 0; off >>= 1) {
      v1 += __shfl_xor(v1, off, 64);
      v2 += __shfl_xor(v2, off, 64);
    }
    const int r = bid * 16 + w * 4 + g;
    if (f == 0) { s_src[r] = v1; s_dst[r] = v2; }
    const int c = r >> 5;
    const int quad = (r >> 3) & 3;
    const int vv = r & 7;
    const int tile = f >> 4;
    const int fi = f & 15;
    Hb[(((c * 4 + tile) * 64) + quad * 16 + fi) * 8 + vv] = f2bf_rne(hv[g]);
  }
}

// gat v5: NO barriers in the K-loop, no producer/consumer LDS handoff.
// Block = 16 rows, 8 waves; wave w owns j in [w*1024,(w+1)*1024), 32 steps.
// Per step each lane builds its OWN A-fragment in registers: 8 p-values for
// row m=lane&15, j = w*1024+s*32+quad*8+v, using 8 mask bits (one LDS u32
// broadcast) + s_dst from LDS (loaded once). Denominator = 5th MFMA vs
// all-ones B-tile (exact same sum of bf16(p) in fp32).
__global__ __launch_bounds__(512, 4) void gat_kernel(
    const unsigned* __restrict__ maskw, const short8* __restrict__ Hb,
    const float* __restrict__ s_src, const float* __restrict__ s_dst,
    float* __restrict__ out) {
  __shared__ float shmem[8192];        // 32 KB: s_dst during loop; part[] after
  __shared__ unsigned maskS[16][PADW]; // 16.6 KB: block's mask slice
  __shared__ float dpartS[8][16];
  float* s_dstS = shmem;
  float (*part)[16][64] = (float(*)[16][64])shmem;

  const int tid = threadIdx.x;
  const int w = tid >> 6;
  const int lane = tid & 63;
  const int m = lane & 15;
  const int quad = lane >> 4;
  const int i0 = blockIdx.x * 16;

  // ---- preload (once): s_dst -> LDS (32 KB), mask slice -> LDS (16 KB) ----
  {
    const float4* sd4 = (const float4*)s_dst;
    float4* ls4 = (float4*)s_dstS;
#pragma unroll
    for (int k = 0; k < 4; ++k) ls4[tid + k * 512] = sd4[tid + k * 512];
    const int mr = tid >> 5;          // 0..15
    const int cw = (tid & 31) * 8;    // 8 u32 per thread
    const uint4* gm = (const uint4*)(maskw + (size_t)(i0 + mr) * 256 + cw);
    uint4 u0 = gm[0], u1 = gm[1];
    *(uint4*)&maskS[mr][cw] = u0;     // PADW=260 -> rows 16B-aligned
    *(uint4*)&maskS[mr][cw + 4] = u1;
  }
  const float ssrc = s_src[i0 + m];
  short8 onesB;
#pragma unroll
  for (int v = 0; v < 8; ++v) onesB[v] = (short)0x3F80;  // bf16 1.0
  __syncthreads();

  floatx4 acc0 = {0.f, 0.f, 0.f, 0.f};
  floatx4 acc1 = acc0, acc2 = acc0, acc3 = acc0, acc4 = acc0;

  // Hb B-fragments for step 0
  const short8* hp = Hb + (size_t)(w * 32) * 256 + lane;
  short8 h0 = hp[0], h1 = hp[64], h2 = hp[128], h3 = hp[192];

  for (int s = 0; s < 32; ++s) {
    // prefetch next step's B-fragments (L2-resident; only vmem in loop)
    short8 n0, n1, n2, n3;
    if (s + 1 < 32) {
      const short8* np = Hb + (size_t)(w * 32 + s + 1) * 256 + lane;
      n0 = np[0]; n1 = np[64]; n2 = np[128]; n3 = np[192];
    }
    // mask bits + s_dst for this lane's 8 j's
    unsigned mword = maskS[m][w * 32 + s];
    unsigned bits8 = (mword >> (quad * 8)) & 0xFFu;
    const float* sp = s_dstS + w * 1024 + s * 32 + quad * 8;
    float4 sd0 = *(const float4*)sp;
    float4 sd1 = *(const float4*)(sp + 4);
    float sv[8] = {sd0.x, sd0.y, sd0.z, sd0.w, sd1.x, sd1.y, sd1.z, sd1.w};
    short8 af;
#pragma unroll
    for (int v = 0; v < 8; ++v) {
      float tt = ssrc + sv[v];
      float e = fmaxf(tt, 0.f) + 0.01f * fminf(tt, 0.f);  // leaky_relu
      float p = __expf(e);
      p = ((bits8 >> v) & 1u) ? p : 0.f;
      af[v] = f2bf_rne(p);
    }
    acc0 = __builtin_amdgcn_mfma_f32_16x16x32_bf16(af, h0, acc0, 0, 0, 0);
    acc1 = __builtin_amdgcn_mfma_f32_16x16x32_bf16(af, h1, acc1, 0, 0, 0);
    acc2 = __builtin_amdgcn_mfma_f32_16x16x32_bf16(af, h2, acc2, 0, 0, 0);
    acc3 = __builtin_amdgcn_mfma_f32_16x16x32_bf16(af, h3, acc3, 0, 0, 0);
    acc4 = __builtin_amdgcn_mfma_f32_16x16x32_bf16(af, onesB, acc4, 0, 0, 0);  // denom
    h0 = n0; h1 = n1; h2 = n2; h3 = n3;
  }

  __syncthreads();  // all waves done reading s_dstS; safe to overwrite with part

  // C/D layout: col = lane&15, row = quad*4 + reg
  const int col = lane & 15;
#pragma unroll
  for (int rg = 0; rg < 4; ++rg) {
    part[w][quad * 4 + rg][col]      = acc0[rg];
    part[w][quad * 4 + rg][16 + col] = acc1[rg];
    part[w][quad * 4 + rg][32 + col] = acc2[rg];
    part[w][quad * 4 + rg][48 + col] = acc3[rg];
  }
  if (col == 0) {
#pragma unroll
    for (int rg = 0; rg < 4; ++rg) dpartS[w][quad * 4 + rg] = acc4[rg];
  }
  __syncthreads();

  // epilogue: sum 8 wave-partials (disjoint j), normalize, ELU, coalesced store
  for (int idx = tid; idx < 16 * 64; idx += 512) {
    int mr = idx >> 6, fc = idx & 63;
    float num = 0.f, den = 0.f;
#pragma unroll
    for (int ww = 0; ww < 8; ++ww) { num += part[ww][mr][fc]; den += dpartS[ww][mr]; }
    float o = num / den;
    o = (o > 0.f) ? o : (__expf(o) - 1.f);
    out[(size_t)(i0 + mr) * FOUT + fc] = o;
  }
}

extern "C" void kernel_launch(void* const* d_in, const int* in_sizes, int n_in,
                              void* d_out, int out_size, void* d_ws, size_t ws_size,
                              hipStream_t stream) {
  const float* x     = (const float*)d_in[0];
  const int*   adj   = (const int*)d_in[1];
  const float* W     = (const float*)d_in[2];
  const float* att_w = (const float*)d_in[3];
  float* out = (float*)d_out;
  char* ws = (char*)d_ws;
  short* Hb = (short*)ws;                                   // 1 MB bf16 swizzled h
  float* s_src = (float*)(ws + (size_t)NN * FOUT * sizeof(short));
  float* s_dst = s_src + NN;
  unsigned long long* mask = (unsigned long long*)(ws + (2u << 20));  // 8 MB straight bitmask
  convert_kernel<<<NN / 4, 256, 0, stream>>>(adj, mask);
  prep_kernel<<<NN / 16, 256, 0, stream>>>(x, W, att_w, Hb, s_src, s_dst);
  gat_kernel<<<NN / 16, 512, 0, stream>>>((const unsigned*)mask, (const short8*)Hb,
                                          s_src, s_dst, out);
}

// Round 9
// 377.971 us; speedup vs baseline: 1.1167x; 1.0618x over previous
//
#include <hip/hip_runtime.h>
#include <hip/hip_bf16.h>

#define NN 8192
#define FIN 128
#define FOUT 64
#define MSTR 12   // maskL row stride in u32 (8 words + 4 pad; rows 48B -> 16B-aligned)

typedef __attribute__((ext_vector_type(8))) short short8;
typedef __attribute__((ext_vector_type(4))) float floatx4;

__device__ __forceinline__ short f2bf_rne(float x) {
  union { float f; unsigned u; } c; c.f = x;
  unsigned r = c.u + 0x7fffu + ((c.u >> 16) & 1u);
  return (short)(r >> 16);
}

// Kernel A: h = x @ W^T (fp32), s_src/s_dst, and Hb = bf16 h pre-swizzled into
// MFMA-B-fragment order: Hb[((c*4 + ftile)*64 + quad*16 + fi)*8 + v] = h[c*32+quad*8+v][ftile*16+fi]
__global__ __launch_bounds__(256) void prep_kernel(
    const float* __restrict__ x, const float* __restrict__ W,
    const float* __restrict__ att_w,
    short* __restrict__ Hb, float* __restrict__ s_src, float* __restrict__ s_dst) {
  __shared__ float xs[16 * FIN];  // 8 KB: 16 rows of x
  const int t = threadIdx.x;
  const int bid = blockIdx.x;
#pragma unroll
  for (int i = 0; i < 8; ++i)
    xs[t + i * 256] = x[(size_t)bid * (16 * FIN) + t + i * 256];
  __syncthreads();
  const int w = t >> 6;     // wave handles rows w*4 .. w*4+3
  const int f = t & 63;     // lane == output feature
  const float4* Wf4 = (const float4*)(W + f * FIN);
  const float4* xr0 = (const float4*)(xs + (w * 4 + 0) * FIN);
  const float4* xr1 = (const float4*)(xs + (w * 4 + 1) * FIN);
  const float4* xr2 = (const float4*)(xs + (w * 4 + 2) * FIN);
  const float4* xr3 = (const float4*)(xs + (w * 4 + 3) * FIN);
  float h0 = 0.f, h1 = 0.f, h2 = 0.f, h3 = 0.f;
#pragma unroll
  for (int k = 0; k < FIN / 4; ++k) {
    float4 wv = Wf4[k];
    float4 v0 = xr0[k], v1 = xr1[k], v2 = xr2[k], v3 = xr3[k];
    h0 = fmaf(v0.x, wv.x, h0); h0 = fmaf(v0.y, wv.y, h0);
    h0 = fmaf(v0.z, wv.z, h0); h0 = fmaf(v0.w, wv.w, h0);
    h1 = fmaf(v1.x, wv.x, h1); h1 = fmaf(v1.y, wv.y, h1);
    h1 = fmaf(v1.z, wv.z, h1); h1 = fmaf(v1.w, wv.w, h1);
    h2 = fmaf(v2.x, wv.x, h2); h2 = fmaf(v2.y, wv.y, h2);
    h2 = fmaf(v2.z, wv.z, h2); h2 = fmaf(v2.w, wv.w, h2);
    h3 = fmaf(v3.x, wv.x, h3); h3 = fmaf(v3.y, wv.y, h3);
    h3 = fmaf(v3.z, wv.z, h3); h3 = fmaf(v3.w, wv.w, h3);
  }
  const float asrc = att_w[f];
  const float adst = att_w[FOUT + f];
  float hv[4] = {h0, h1, h2, h3};
#pragma unroll
  for (int g = 0; g < 4; ++g) {
    float v1 = hv[g] * asrc;
    float v2 = hv[g] * adst;
#pragma unroll
    for (int off = 32; off > 0; off >>= 1) {
      v1 += __shfl_xor(v1, off, 64);
      v2 += __shfl_xor(v2, off, 64);
    }
    const int r = bid * 16 + w * 4 + g;
    if (f == 0) { s_src[r] = v1; s_dst[r] = v2; }
    const int c = r >> 5;
    const int quad = (r >> 3) & 3;
    const int vv = r & 7;
    const int tile = f >> 4;
    const int fi = f & 15;
    Hb[(((c * 4 + tile) * 64) + quad * 16 + fi) * 8 + vv] = f2bf_rne(hv[g]);
  }
}

// gat v6: single fused pass over adj. Block = 16 rows, 8 waves, 32 chunks of
// 256 j. Produce: wave w streams adj rows 2w,2w+1 (1 KB contiguous per row per
// chunk, the R5-winning pattern), ballots bits into a tiny double-buffered LDS
// mask (straight layout: u32 word wi of row r = adj bits [wi*32,wi*32+32)).
// Consume (R8-style, register-built A-frags): lane = row m, j = c*256 + w*32 +
// quad*8 + v; p from LDS-resident s_dst + mask bits; 4 feature MFMAs + 1
// ones-MFMA for the denominator. ONE barrier per chunk.
__global__ __launch_bounds__(512, 4) void gat_kernel(
    const int* __restrict__ adj, const short8* __restrict__ Hb,
    const float* __restrict__ s_src, const float* __restrict__ s_dst,
    float* __restrict__ out) {
  __shared__ float shmem[8192];            // 32 KB: s_dst during loop; part[] after
  __shared__ unsigned maskL[2][16][MSTR];  // 1.5 KB: double-buffered mask slice
  __shared__ float dpartS[8][16];
  float* s_dstS = shmem;
  float (*part)[16][64] = (float(*)[16][64])shmem;

  const int tid = threadIdx.x;
  const int w = tid >> 6;
  const int lane = tid & 63;
  const int m = lane & 15;
  const int quad = lane >> 4;
  const int i0 = blockIdx.x * 16;
  const int rA = 2 * w, rB = 2 * w + 1;

  // ---- preload s_dst -> LDS (32 KB, once) ----
  {
    const float4* sd4 = (const float4*)s_dst;
    float4* ls4 = (float4*)s_dstS;
#pragma unroll
    for (int k = 0; k < 4; ++k) ls4[tid + k * 512] = sd4[tid + k * 512];
  }
  const float ssrc = s_src[i0 + m];
  short8 onesB;
#pragma unroll
  for (int v = 0; v < 8; ++v) onesB[v] = (short)0x3F80;  // bf16 1.0

  const int* adjA = adj + (size_t)(i0 + rA) * NN + lane;
  const int* adjB = adj + (size_t)(i0 + rB) * NN + lane;

  // ---- prologue: chunk 0 bits -> maskL[0]; issue chunk-1 loads ----
  int a0A = __builtin_nontemporal_load(adjA + 0);
  int a1A = __builtin_nontemporal_load(adjA + 64);
  int a2A = __builtin_nontemporal_load(adjA + 128);
  int a3A = __builtin_nontemporal_load(adjA + 192);
  int a0B = __builtin_nontemporal_load(adjB + 0);
  int a1B = __builtin_nontemporal_load(adjB + 64);
  int a2B = __builtin_nontemporal_load(adjB + 128);
  int a3B = __builtin_nontemporal_load(adjB + 192);
  {
    unsigned long long bA0 = __ballot(a0A > 0), bA1 = __ballot(a1A > 0);
    unsigned long long bA2 = __ballot(a2A > 0), bA3 = __ballot(a3A > 0);
    unsigned long long bB0 = __ballot(a0B > 0), bB1 = __ballot(a1B > 0);
    unsigned long long bB2 = __ballot(a2B > 0), bB3 = __ballot(a3B > 0);
    if (lane == 0) {
      *(uint4*)&maskL[0][rA][0] = uint4{(unsigned)bA0, (unsigned)(bA0 >> 32),
                                        (unsigned)bA1, (unsigned)(bA1 >> 32)};
      *(uint4*)&maskL[0][rA][4] = uint4{(unsigned)bA2, (unsigned)(bA2 >> 32),
                                        (unsigned)bA3, (unsigned)(bA3 >> 32)};
      *(uint4*)&maskL[0][rB][0] = uint4{(unsigned)bB0, (unsigned)(bB0 >> 32),
                                        (unsigned)bB1, (unsigned)(bB1 >> 32)};
      *(uint4*)&maskL[0][rB][4] = uint4{(unsigned)bB2, (unsigned)(bB2 >> 32),
                                        (unsigned)bB3, (unsigned)(bB3 >> 32)};
    }
  }
  a0A = __builtin_nontemporal_load(adjA + 256);
  a1A = __builtin_nontemporal_load(adjA + 320);
  a2A = __builtin_nontemporal_load(adjA + 384);
  a3A = __builtin_nontemporal_load(adjA + 448);
  a0B = __builtin_nontemporal_load(adjB + 256);
  a1B = __builtin_nontemporal_load(adjB + 320);
  a2B = __builtin_nontemporal_load(adjB + 384);
  a3B = __builtin_nontemporal_load(adjB + 448);
  __syncthreads();

  floatx4 acc0 = {0.f, 0.f, 0.f, 0.f};
  floatx4 acc1 = acc0, acc2 = acc0, acc3 = acc0, acc4 = acc0;

  for (int c = 0; c < 32; ++c) {
    // 1) Hb B-fragments for this chunk's k-strip (L2-resident)
    const short8* hp = Hb + (size_t)(c * 8 + w) * 256 + lane;
    short8 h0 = hp[0], h1 = hp[64], h2 = hp[128], h3 = hp[192];
    // 2) ballot chunk c+1 (regs from prior iter), publish to maskL[(c+1)&1]
    if (c + 1 < 32) {
      unsigned long long bA0 = __ballot(a0A > 0), bA1 = __ballot(a1A > 0);
      unsigned long long bA2 = __ballot(a2A > 0), bA3 = __ballot(a3A > 0);
      unsigned long long bB0 = __ballot(a0B > 0), bB1 = __ballot(a1B > 0);
      unsigned long long bB2 = __ballot(a2B > 0), bB3 = __ballot(a3B > 0);
      if (lane == 0) {
        const int nb = (c + 1) & 1;
        *(uint4*)&maskL[nb][rA][0] = uint4{(unsigned)bA0, (unsigned)(bA0 >> 32),
                                           (unsigned)bA1, (unsigned)(bA1 >> 32)};
        *(uint4*)&maskL[nb][rA][4] = uint4{(unsigned)bA2, (unsigned)(bA2 >> 32),
                                           (unsigned)bA3, (unsigned)(bA3 >> 32)};
        *(uint4*)&maskL[nb][rB][0] = uint4{(unsigned)bB0, (unsigned)(bB0 >> 32),
                                           (unsigned)bB1, (unsigned)(bB1 >> 32)};
        *(uint4*)&maskL[nb][rB][4] = uint4{(unsigned)bB2, (unsigned)(bB2 >> 32),
                                           (unsigned)bB3, (unsigned)(bB3 >> 32)};
      }
      // 3) issue adj loads for chunk c+2 (only HBM stream)
      if (c + 2 < 32) {
        const int* pA = adjA + (c + 2) * 256;
        const int* pB = adjB + (c + 2) * 256;
        a0A = __builtin_nontemporal_load(pA + 0);
        a1A = __builtin_nontemporal_load(pA + 64);
        a2A = __builtin_nontemporal_load(pA + 128);
        a3A = __builtin_nontemporal_load(pA + 192);
        a0B = __builtin_nontemporal_load(pB + 0);
        a1B = __builtin_nontemporal_load(pB + 64);
        a2B = __builtin_nontemporal_load(pB + 128);
        a3B = __builtin_nontemporal_load(pB + 192);
      }
    }
    // 4) consume chunk c: bits + s_dst -> 8 p-values -> A-frag (registers)
    unsigned word = maskL[c & 1][m][w];
    unsigned bits8 = (word >> (quad * 8)) & 0xFFu;
    const float* sp = s_dstS + c * 256 + w * 32 + quad * 8;
    float4 sd0 = *(const float4*)sp;
    float4 sd1 = *(const float4*)(sp + 4);
    float sv[8] = {sd0.x, sd0.y, sd0.z, sd0.w, sd1.x, sd1.y, sd1.z, sd1.w};
    short8 af;
#pragma unroll
    for (int v = 0; v < 8; ++v) {
      float tt = ssrc + sv[v];
      float e = fmaxf(tt, 0.f) + 0.01f * fminf(tt, 0.f);  // leaky_relu
      float p = __expf(e);
      p = ((bits8 >> v) & 1u) ? p : 0.f;
      af[v] = f2bf_rne(p);
    }
    acc0 = __builtin_amdgcn_mfma_f32_16x16x32_bf16(af, h0, acc0, 0, 0, 0);
    acc1 = __builtin_amdgcn_mfma_f32_16x16x32_bf16(af, h1, acc1, 0, 0, 0);
    acc2 = __builtin_amdgcn_mfma_f32_16x16x32_bf16(af, h2, acc2, 0, 0, 0);
    acc3 = __builtin_amdgcn_mfma_f32_16x16x32_bf16(af, h3, acc3, 0, 0, 0);
    acc4 = __builtin_amdgcn_mfma_f32_16x16x32_bf16(af, onesB, acc4, 0, 0, 0);  // denom
    __syncthreads();  // publish maskL[(c+1)&1]; guard maskL[c&1] reuse
  }

  // C/D layout: col = lane&15, row = quad*4 + reg. shmem reuse is safe: the
  // loop's final barrier orders all s_dstS reads before these writes.
  const int col = lane & 15;
#pragma unroll
  for (int rg = 0; rg < 4; ++rg) {
    part[w][quad * 4 + rg][col]      = acc0[rg];
    part[w][quad * 4 + rg][16 + col] = acc1[rg];
    part[w][quad * 4 + rg][32 + col] = acc2[rg];
    part[w][quad * 4 + rg][48 + col] = acc3[rg];
  }
  if (col == 0) {
#pragma unroll
    for (int rg = 0; rg < 4; ++rg) dpartS[w][quad * 4 + rg] = acc4[rg];
  }
  __syncthreads();

  // epilogue: sum 8 wave-partials (disjoint j), normalize, ELU, coalesced store
  for (int idx = tid; idx < 16 * 64; idx += 512) {
    int mr = idx >> 6, fc = idx & 63;
    float num = 0.f, den = 0.f;
#pragma unroll
    for (int ww = 0; ww < 8; ++ww) { num += part[ww][mr][fc]; den += dpartS[ww][mr]; }
    float o = num / den;
    o = (o > 0.f) ? o : (__expf(o) - 1.f);
    out[(size_t)(i0 + mr) * FOUT + fc] = o;
  }
}

extern "C" void kernel_launch(void* const* d_in, const int* in_sizes, int n_in,
                              void* d_out, int out_size, void* d_ws, size_t ws_size,
                              hipStream_t stream) {
  const float* x     = (const float*)d_in[0];
  const int*   adj   = (const int*)d_in[1];
  const float* W     = (const float*)d_in[2];
  const float* att_w = (const float*)d_in[3];
  float* out = (float*)d_out;
  char* ws = (char*)d_ws;
  short* Hb = (short*)ws;                                   // 1 MB bf16 swizzled h
  float* s_src = (float*)(ws + (size_t)NN * FOUT * sizeof(short));
  float* s_dst = s_src + NN;
  prep_kernel<<<NN / 16, 256, 0, stream>>>(x, W, att_w, Hb, s_src, s_dst);
  gat_kernel<<<NN / 16, 512, 0, stream>>>(adj, (const short8*)Hb, s_src, s_dst, out);
}